// Round 1
// baseline (330.634 us; speedup 1.0000x reference)
//
#include <hip/hip_runtime.h>
#include <stdint.h>

#define NUM_CAP 16
#define DIM_CAP 64
#define BATCH   64
#define N_IN    512
#define D_IN    1024
#define N_COL   1024
#define M_ROWS  (BATCH*N_IN)

typedef __attribute__((ext_vector_type(8))) short short8;
typedef __attribute__((ext_vector_type(4))) float f32x4;

__device__ __forceinline__ float bf2f(unsigned int u) {
  return __uint_as_float(u << 16);
}
__device__ __forceinline__ unsigned short f2bf_rne(float f) {
  unsigned int x = __float_as_uint(f);
  x += 0x7fffu + ((x >> 16) & 1u);
  return (unsigned short)(x >> 16);
}
__device__ __forceinline__ unsigned int pack_rne(unsigned int lo, unsigned int hi) {
  const unsigned int lr = lo + (0x7fffu + ((lo >> 16) & 1u));
  const unsigned int hr = hi + (0x7fffu + ((hi >> 16) & 1u));
  return (lr >> 16) | (hr & 0xffff0000u);
}

// ---------------------------------------------------------------------------
// prep: blocks [0,16384) convert x fp32->bf16 (8 elems/thread, coalesced);
// blocks [16384, 16384+1024) transpose+convert W -> Wt[n][k].
// ---------------------------------------------------------------------------
__global__ __launch_bounds__(256) void prep(
    const float* __restrict__ x, const float* __restrict__ W,
    unsigned short* __restrict__ xb, unsigned short* __restrict__ Wt) {
  const int t = threadIdx.x;
  if (blockIdx.x < 16384) {
    const size_t i = ((size_t)blockIdx.x * 256 + t) * 8;
    const uint4 a = *(const uint4*)(x + i);
    const uint4 b = *(const uint4*)(x + i + 4);
    uint4 p;
    p.x = pack_rne(a.x, a.y); p.y = pack_rne(a.z, a.w);
    p.z = pack_rne(b.x, b.y); p.w = pack_rne(b.z, b.w);
    *(uint4*)(xb + i) = p;
  } else {
    __shared__ float tile[32][33];
    const int bid = blockIdx.x - 16384;       // 0..1023
    const int bx = bid & 31, by = bid >> 5;   // 32x32 tiles
    const int tx = t & 31, ty0 = t >> 5;      // 8 rows per pass
    #pragma unroll
    for (int r = 0; r < 4; r++) {
      const int ty = ty0 + r * 8;
      tile[ty][tx] = W[(size_t)(by * 32 + ty) * N_COL + bx * 32 + tx];
    }
    __syncthreads();
    #pragma unroll
    for (int r = 0; r < 4; r++) {
      const int ty = ty0 + r * 8;
      Wt[(size_t)(bx * 32 + ty) * D_IN + by * 32 + tx] = f2bf_rne(tile[tx][ty]);
    }
  }
}

// ---------------------------------------------------------------------------
// GEMM — R3-measured structure (VGPR 72, conflicts 0): both operands bf16 via
// global_load_lds width=16, XOR-swizzled LDS (position chunk c of row r holds
// global chunk c^((r>>1)&3)), plus the R4/R6-measured XCD map (FETCH 265->65
// MB): xcd=blockIdx&7 owns mt in [xcd*32,+32), nt sweeps fastest so A-tile
// sharers hit the same XCD L2.
//
// NEW (this round): fused strip-sum epilogue replaces the s1q kernel.  The
// 64-row strip sums needed for routing iter-1 are already in the f32
// accumulators: each wave's 64x64 sub-tile lies entirely inside one
// (b, strip) = row-block mt*2+wm, cols n0+wn*64..+64.  Column sums = 16 adds
// per frag column + shfl_xor(16,32) + one f32 store from lanes 0..15.  No
// atomics: each (strip,col) is owned by exactly one block.  This is register-
// resident (unlike R6's failed squash-fusion that cost VGPR 72->100) and
// eliminates a full 64 MB re-read of uhat.
// ---------------------------------------------------------------------------
__global__ __launch_bounds__(256) void gemm_uhat(
    const unsigned short* __restrict__ A,    // [M_ROWS][D_IN] bf16
    const unsigned short* __restrict__ Bt,   // [N_COL][D_IN] bf16
    unsigned short* __restrict__ C,          // [M_ROWS][N_COL] bf16
    float* __restrict__ S1) {                // [BATCH][8][N_COL] strip sums
  __shared__ __align__(16) unsigned short lA[128 * 32];
  __shared__ __align__(16) unsigned short lB[128 * 32];

  const int t = threadIdx.x;
  const int wave = t >> 6, lane = t & 63;
  const int xcd = blockIdx.x & 7, local = blockIdx.x >> 3;
  const int mt = xcd * 32 + (local >> 3), nt = local & 7;
  const int m0 = mt * 128, n0 = nt * 128;
  const int wm = wave & 1, wn = wave >> 1;

  f32x4 acc[4][4] = {};

  const int srow = lane >> 2;
  const int schunk = ((lane & 3) ^ ((srow >> 1) & 3)) * 8;  // swizzled source chunk

  for (int kt = 0; kt < D_IN / 32; ++kt) {
    const int k0 = kt * 32;
    __syncthreads();
    #pragma unroll
    for (int s0 = 0; s0 < 2; ++s0) {
      const int s = wave + s0 * 4;
      const unsigned short* ga = A + (size_t)(m0 + s * 16 + srow) * D_IN + k0 + schunk;
      __builtin_amdgcn_global_load_lds(
          (const __attribute__((address_space(1))) void*)ga,
          (__attribute__((address_space(3))) void*)(lA + s * 512), 16, 0, 0);
      const unsigned short* gb = Bt + (size_t)(n0 + s * 16 + srow) * D_IN + k0 + schunk;
      __builtin_amdgcn_global_load_lds(
          (const __attribute__((address_space(1))) void*)gb,
          (__attribute__((address_space(3))) void*)(lB + s * 512), 16, 0, 0);
    }
    __syncthreads();

    short8 af[4], bfr[4];
    const int rsel = lane & 15;
    const int q = lane >> 4;
    const int koff = (q ^ ((rsel >> 1) & 3)) * 8;
    #pragma unroll
    for (int tm = 0; tm < 4; tm++)
      af[tm] = *(const short8*)&lA[(wm * 64 + tm * 16 + rsel) * 32 + koff];
    #pragma unroll
    for (int tn = 0; tn < 4; tn++)
      bfr[tn] = *(const short8*)&lB[(wn * 64 + tn * 16 + rsel) * 32 + koff];
    #pragma unroll
    for (int tm = 0; tm < 4; tm++)
      #pragma unroll
      for (int tn = 0; tn < 4; tn++)
        acc[tm][tn] = __builtin_amdgcn_mfma_f32_16x16x32_bf16(
            af[tm], bfr[tn], acc[tm][tn], 0, 0, 0);
  }

  // C/D layout col=lane&15, row=(lane>>4)*4+reg  [m89-verified]
  const int lrow = (lane >> 4) * 4, lcol = lane & 15;
  #pragma unroll
  for (int tm = 0; tm < 4; tm++)
    #pragma unroll
    for (int tn = 0; tn < 4; tn++)
      #pragma unroll
      for (int r = 0; r < 4; r++) {
        const int row = m0 + wm * 64 + tm * 16 + lrow + r;
        const int col = n0 + wn * 64 + tn * 16 + lcol;
        C[(size_t)row * N_COL + col] = f2bf_rne(acc[tm][tn][r]);
      }

  // fused strip-sum epilogue (replaces s1q): sum this wave's 64 rows per col.
  float scol[4];
  #pragma unroll
  for (int tn = 0; tn < 4; tn++) {
    float s = 0.f;
    #pragma unroll
    for (int tm = 0; tm < 4; tm++)
      #pragma unroll
      for (int r = 0; r < 4; r++) s += acc[tm][tn][r];
    s += __shfl_xor(s, 16);   // fold the four 16-lane row groups
    s += __shfl_xor(s, 32);
    scol[tn] = s;
  }
  if (lane < 16) {
    const size_t sbase = (size_t)(mt * 2 + wm) * N_COL + n0 + wn * 64;
    #pragma unroll
    for (int tn = 0; tn < 4; tn++)
      S1[sbase + tn * 16 + lane] = scol[tn];
  }
}

// ---------------------------------------------------------------------------
// Routing iteration: block=(b,jt4).  Phase A (redundant, cheap): sum nstrips
// 1024-float strips of Vin -> s, squash -> v.  Phase B: wave w handles
// jt=jt4*4+w (8 j's); lane l holds uhat[b, i=l>>2, j, k=(l&3)*16..+16];
// b_i dot via quad shuffles; softmax over i (no max-subtract, |b| bounded);
// accumulate c*u; 4-wave LDS reduce -> Pout[blockIdx][i*64+k].
// ---------------------------------------------------------------------------
__global__ __launch_bounds__(256) void route_mid(
    const unsigned short* __restrict__ uhat,
    const float* __restrict__ Vin,
    float* __restrict__ Pout,
    const int nstrips) {
  __shared__ float sq[16 * 68];
  __shared__ float red[4][1024];
  const int t = threadIdx.x;
  const int w = t >> 6, lane = t & 63;
  const int b = blockIdx.x >> 4, jt4 = blockIdx.x & 15;
  const int jt = jt4 * 4 + w;
  const int i_l = lane >> 2, c4 = lane & 3;

  float4 v4 = make_float4(0.f, 0.f, 0.f, 0.f);
  for (int s = 0; s < nstrips; ++s) {
    const float4 ps = *(const float4*)&Vin[((size_t)b * nstrips + s) * 1024 + t * 4];
    v4.x += ps.x; v4.y += ps.y; v4.z += ps.z; v4.w += ps.w;
  }
  float ss = v4.x * v4.x + v4.y * v4.y + v4.z * v4.z + v4.w * v4.w;
  #pragma unroll
  for (int d = 1; d < 16; d <<= 1) ss += __shfl_xor(ss, d);  // 16 lanes = one capsule
  const float inv = 1.f / sqrtf(ss + 1e-7f);
  const int oi = t >> 4, ok = (t & 15) * 4;
  *(float4*)&sq[oi * 68 + ok] =
      make_float4(v4.x * inv, v4.y * inv, v4.z * inv, v4.w * inv);
  __syncthreads();

  float pv[16];
  #pragma unroll
  for (int q = 0; q < 4; q++)
    *(float4*)&pv[q * 4] = *(const float4*)&sq[i_l * 68 + c4 * 16 + q * 4];

  float acc[16];
  #pragma unroll
  for (int q = 0; q < 16; q++) acc[q] = 0.f;

  const unsigned short* ub =
      uhat + (size_t)(b * N_IN + jt * 8) * N_COL + lane * 16;

  for (int jj = 0; jj < 8; ++jj, ub += N_COL) {
    const uint4 d0 = *(const uint4*)ub;
    const uint4 d1 = *(const uint4*)(ub + 8);
    float u[16];
    #define UNP(wd, o) { u[(o)] = bf2f((wd) & 0xffffu); u[(o)+1] = __uint_as_float((wd) & 0xffff0000u); }
    UNP(d0.x, 0) UNP(d0.y, 2) UNP(d0.z, 4) UNP(d0.w, 6)
    UNP(d1.x, 8) UNP(d1.y, 10) UNP(d1.z, 12) UNP(d1.w, 14)
    #undef UNP

    float dot = 0.f;
    #pragma unroll
    for (int q = 0; q < 16; q++) dot = fmaf(pv[q], u[q], dot);
    dot += __shfl_xor(dot, 1);
    dot += __shfl_xor(dot, 2);
    const float e = __expf(dot);
    float s = e;
    #pragma unroll
    for (int d = 4; d < 64; d <<= 1) s += __shfl_xor(s, d);
    const float c = e / s;
    #pragma unroll
    for (int q = 0; q < 16; q++) acc[q] = fmaf(c, u[q], acc[q]);
  }

  #pragma unroll
  for (int q = 0; q < 4; q++)
    *(float4*)&red[w][lane * 16 + q * 4] = make_float4(
        acc[q * 4 + 0], acc[q * 4 + 1], acc[q * 4 + 2], acc[q * 4 + 3]);
  __syncthreads();
  float4 s4 = make_float4(0.f, 0.f, 0.f, 0.f);
  #pragma unroll
  for (int ww = 0; ww < 4; ++ww) {
    const float4 r = *(const float4*)&red[ww][t * 4];
    s4.x += r.x; s4.y += r.y; s4.z += r.z; s4.w += r.w;
  }
  *(float4*)&Pout[(size_t)blockIdx.x * 1024 + t * 4] = s4;
}

// ---------------------------------------------------------------------------
__global__ __launch_bounds__(64) void route_last(
    const float* __restrict__ P, float* __restrict__ dst) {
  const int bi = blockIdx.x;
  const int k = threadIdx.x;
  const int b = bi >> 4, i = bi & 15;
  const float* p = P + (size_t)b * 16 * 1024 + i * 64 + k;
  float s = 0.f;
  #pragma unroll
  for (int tt = 0; tt < 16; ++tt) s += p[(size_t)tt * 1024];
  float ss = s * s;
  #pragma unroll
  for (int d = 1; d < 64; d <<= 1) ss += __shfl_xor(ss, d);
  dst[bi * 64 + k] = s / sqrtf(ss + 1e-7f);
}

// ---------------------------------------------------------------------------
extern "C" void kernel_launch(void* const* d_in, const int* in_sizes, int n_in,
                              void* d_out, int out_size, void* d_ws, size_t ws_size,
                              hipStream_t stream) {
  const float* x = (const float*)d_in[0];   // [64][512][1024] fp32
  const float* W = (const float*)d_in[1];   // [1][1024][1024] fp32
  float* out = (float*)d_out;               // [64][16][64] fp32

  char* ws = (char*)d_ws;
  unsigned short* Wt   = (unsigned short*)ws;                            // 0..2 MB
  unsigned short* uhat = (unsigned short*)(ws + (size_t)(2 << 20));      // 2..66 MB
  unsigned short* xb   = (unsigned short*)(ws + (size_t)66 * (1 << 20)); // 66..130 (dead after gemm)
  float* S1 = (float*)(ws + (size_t)130 * (1 << 20));                    // 130..132 MB
  float* P1 = (float*)(ws + (size_t)66 * (1 << 20));   // reuses dead xb
  float* P2 = (float*)(ws + (size_t)71 * (1 << 20));   // reuses dead xb

  prep<<<16384 + 1024, 256, 0, stream>>>(x, W, xb, Wt);
  gemm_uhat<<<2048, 256, 0, stream>>>(xb, Wt, uhat, S1);  // S1 fused (s1q removed)
  route_mid<<<1024, 256, 0, stream>>>(uhat, S1, P1, 8);   // routing iter 2
  route_mid<<<1024, 256, 0, stream>>>(uhat, P1, P2, 16);  // routing iter 3
  route_last<<<1024, 64, 0, stream>>>(P2, out);
}

// Round 2
// 312.761 us; speedup vs baseline: 1.0571x; 1.0571x over previous
//
#include <hip/hip_runtime.h>
#include <stdint.h>

#define NUM_CAP 16
#define DIM_CAP 64
#define BATCH   64
#define N_IN    512
#define D_IN    1024
#define N_COL   1024
#define M_ROWS  (BATCH*N_IN)

typedef __attribute__((ext_vector_type(8))) short short8;
typedef __attribute__((ext_vector_type(4))) float f32x4;

__device__ __forceinline__ float bf2f(unsigned int u) {
  return __uint_as_float(u << 16);
}
__device__ __forceinline__ unsigned short f2bf_rne(float f) {
  unsigned int x = __float_as_uint(f);
  x += 0x7fffu + ((x >> 16) & 1u);
  return (unsigned short)(x >> 16);
}
__device__ __forceinline__ unsigned int pack_rne(unsigned int lo, unsigned int hi) {
  const unsigned int lr = lo + (0x7fffu + ((lo >> 16) & 1u));
  const unsigned int hr = hi + (0x7fffu + ((hi >> 16) & 1u));
  return (lr >> 16) | (hr & 0xffff0000u);
}

// ---------------------------------------------------------------------------
// prep: blocks [0,16384) convert x fp32->bf16 (8 elems/thread, coalesced);
// blocks [16384, 16384+1024) transpose+convert W -> Wt[n][k].
// ---------------------------------------------------------------------------
__global__ __launch_bounds__(256) void prep(
    const float* __restrict__ x, const float* __restrict__ W,
    unsigned short* __restrict__ xb, unsigned short* __restrict__ Wt) {
  const int t = threadIdx.x;
  if (blockIdx.x < 16384) {
    const size_t i = ((size_t)blockIdx.x * 256 + t) * 8;
    const uint4 a = *(const uint4*)(x + i);
    const uint4 b = *(const uint4*)(x + i + 4);
    uint4 p;
    p.x = pack_rne(a.x, a.y); p.y = pack_rne(a.z, a.w);
    p.z = pack_rne(b.x, b.y); p.w = pack_rne(b.z, b.w);
    *(uint4*)(xb + i) = p;
  } else {
    __shared__ float tile[32][33];
    const int bid = blockIdx.x - 16384;       // 0..1023
    const int bx = bid & 31, by = bid >> 5;   // 32x32 tiles
    const int tx = t & 31, ty0 = t >> 5;      // 8 rows per pass
    #pragma unroll
    for (int r = 0; r < 4; r++) {
      const int ty = ty0 + r * 8;
      tile[ty][tx] = W[(size_t)(by * 32 + ty) * N_COL + bx * 32 + tx];
    }
    __syncthreads();
    #pragma unroll
    for (int r = 0; r < 4; r++) {
      const int ty = ty0 + r * 8;
      Wt[(size_t)(bx * 32 + ty) * D_IN + by * 32 + tx] = f2bf_rne(tile[tx][ty]);
    }
  }
}

// ---------------------------------------------------------------------------
// GEMM — 256^2 x BK64 8-phase schedule (T2+T3+T4+T5 port, plain HIP).
// 8 waves as 2(m) x 4(n); wave tile 128x64 built from INTERLEAVED quadrants:
// wave (wm,wn) at quadrant (qm,qn) computes rows qm*128+wm*64.., cols
// qn*128+wn*32.. — so each phase reads exactly one A-half (qm) and one
// B-half (qn) of the current K-tile, letting consumed halves be re-staged
// for tile kt+2 one phase after their last read.
//
// Per phase: 12x ds_read_b128 (8 A-frags + 4 B-frags) -> stage one half-tile
// (2x global_load_lds w=16) -> barrier -> setprio(1) 16 MFMA setprio(0) ->
// lgkmcnt(0)+sched_barrier -> counted vmcnt -> barrier.
// Quadrant order per tile: (0,0)(0,1)(1,1)(1,0).
// Stage slots (iter i; u=2i buf0, v=2i+1 buf1):
//   P1: Bh0(v)  P2: Ah1(v)  P3: Ah0(u+2)  P4: Bh1(u+2)
//   P5: Bh0(u+2) P6: Ah1(u+2) P7: Ah0(v+2) P8: Bh1(v+2)
// Waits: end-P2 vmcnt(8), end-P4 vmcnt(6), end-P6 vmcnt(8), end-P8 vmcnt(6);
// steady-state in-flight after each P4/P8 wait = 3 half-tiles (6 calls).
// Last iter (no P3..P8 stages): end-P4 vmcnt(2), end-P6 vmcnt(0).
// LDS layout per matrix: [buf][half][kslice 32][128 rows][32 shorts] with the
// verified 4-chunk XOR swizzle (phys chunk = c ^ ((row>>1)&3)); applied on
// the global SOURCE address at stage time (rule: linear LDS dest) and on the
// ds_read address (both-sides involution). Conflicts were measured 0 with
// this exact scheme at 128^2.
// ---------------------------------------------------------------------------
#define LA_OFF(d, h, ks) (((d)*2 + (h))*2 + (ks)) * 4096
#define LB_OFF(d, h, ks) (32768 + ((((d)*2 + (h))*2 + (ks)) * 4096))

__global__ __launch_bounds__(512) void gemm_uhat(
    const unsigned short* __restrict__ A,    // [M_ROWS][D_IN] bf16
    const unsigned short* __restrict__ Bt,   // [N_COL][D_IN] bf16
    unsigned short* __restrict__ C) {        // [M_ROWS][N_COL] bf16
  __shared__ __align__(16) unsigned short lds[65536];  // 128 KB: A 0.., B 32768..

  const int t = threadIdx.x;
  const int wave = t >> 6, lane = t & 63;
  const int wm = wave >> 2, wn = wave & 3;

  // XCD map: 512 blocks = 128 mt x 4 nt; xcd owns mt range, nt sweeps fastest
  // so the 4 blocks sharing an A-panel land on the same XCD L2. 512%8==0.
  const int xcd = blockIdx.x & 7, local = blockIdx.x >> 3;
  const int mt = xcd * 16 + (local >> 2), nt = local & 3;
  const int m0 = mt * 256, n0 = nt * 256;

  // staging: thread t covers row srl=t/4 of a 128-row half, 16B chunk t%4,
  // source chunk pre-swizzled so linear LDS dest holds the swizzled layout.
  const int srl = t >> 2;
  const int scz = (t & 3) ^ ((t >> 3) & 3);
  const unsigned short* aBase = A  + (size_t)(m0 + srl) * D_IN + scz * 8;
  const unsigned short* bBase = Bt + (size_t)(n0 + srl) * D_IN + scz * 8;

#define STG_A(kt, h) do { \
    _Pragma("unroll") \
    for (int c_ = 0; c_ < 2; ++c_) \
      __builtin_amdgcn_global_load_lds( \
        (const __attribute__((address_space(1))) void*)(aBase + (size_t)(h)*128*D_IN + (kt)*64 + c_*32), \
        (__attribute__((address_space(3))) void*)(lds + (LA_OFF(((kt)&1), (h), c_)) + t*8), \
        16, 0, 0); \
  } while (0)
#define STG_B(kt, h) do { \
    _Pragma("unroll") \
    for (int c_ = 0; c_ < 2; ++c_) \
      __builtin_amdgcn_global_load_lds( \
        (const __attribute__((address_space(1))) void*)(bBase + (size_t)(h)*128*D_IN + (kt)*64 + c_*32), \
        (__attribute__((address_space(3))) void*)(lds + (LB_OFF(((kt)&1), (h), c_)) + t*8), \
        16, 0, 0); \
  } while (0)

  f32x4 acc[2][2][4][2] = {};  // [qm][qn][mf][nf]

  const int rsel = lane & 15;
  const int koff = ((lane >> 4) ^ ((rsel >> 1) & 3)) * 8;  // swizzled read chunk

#define PHASE(d_, qm_, qn_, STAGES, WAITS) do { \
    short8 af[4][2], bfr[2][2]; \
    _Pragma("unroll") \
    for (int mf = 0; mf < 4; ++mf) \
      _Pragma("unroll") \
      for (int ks = 0; ks < 2; ++ks) \
        af[mf][ks] = *(const short8*)&lds[(LA_OFF((d_), (qm_), ks)) + (wm*64 + mf*16 + rsel)*32 + koff]; \
    _Pragma("unroll") \
    for (int nf = 0; nf < 2; ++nf) \
      _Pragma("unroll") \
      for (int ks = 0; ks < 2; ++ks) \
        bfr[nf][ks] = *(const short8*)&lds[(LB_OFF((d_), (qn_), ks)) + (wn*32 + nf*16 + rsel)*32 + koff]; \
    STAGES; \
    __builtin_amdgcn_s_barrier(); \
    __builtin_amdgcn_s_setprio(1); \
    _Pragma("unroll") \
    for (int ks = 0; ks < 2; ++ks) \
      _Pragma("unroll") \
      for (int mf = 0; mf < 4; ++mf) \
        _Pragma("unroll") \
        for (int nf = 0; nf < 2; ++nf) \
          acc[qm_][qn_][mf][nf] = __builtin_amdgcn_mfma_f32_16x16x32_bf16( \
              af[mf][ks], bfr[nf][ks], acc[qm_][qn_][mf][nf], 0, 0, 0); \
    __builtin_amdgcn_s_setprio(0); \
    asm volatile("s_waitcnt lgkmcnt(0)" ::: "memory"); \
    __builtin_amdgcn_sched_barrier(0); \
    WAITS; \
    __builtin_amdgcn_s_barrier(); \
  } while (0)

#define VMC(n) asm volatile("s_waitcnt vmcnt(" #n ")" ::: "memory")

  // prologue: t0 fully + Ah0/Bh1 of t1; drain t0's first 3 halves.
  STG_A(0, 0); STG_B(0, 0); STG_B(0, 1); STG_A(0, 1);
  STG_A(1, 0); STG_B(1, 1);
  VMC(6);
  __builtin_amdgcn_s_barrier();

  for (int i = 0; i < 8; ++i) {
    const int u = 2 * i, v = 2 * i + 1;
    const bool st = (i < 7);
    // ---- tile u (buf0) ----
    PHASE(0, 0, 0, { STG_B(v, 0); }, {});                                  // P1
    PHASE(0, 0, 1, { STG_A(v, 1); }, { VMC(8); });                         // P2
    PHASE(0, 1, 1, { if (st) STG_A(u + 2, 0); }, {});                      // P3
    PHASE(0, 1, 0, { if (st) STG_B(u + 2, 1); },
          { if (st) { VMC(6); } else { VMC(2); } });                       // P4
    // ---- tile v (buf1) ----
    PHASE(1, 0, 0, { if (st) STG_B(u + 2, 0); }, {});                      // P5
    PHASE(1, 0, 1, { if (st) STG_A(u + 2, 1); },
          { if (st) { VMC(8); } else { VMC(0); } });                       // P6
    PHASE(1, 1, 1, { if (st) STG_A(v + 2, 0); }, {});                      // P7
    PHASE(1, 1, 0, { if (st) STG_B(v + 2, 1); }, { VMC(6); });             // P8
  }

  // C/D layout col=lane&15, row=(lane>>4)*4+reg  [m89-verified]
  const int lrow = (lane >> 4) * 4, lcol = lane & 15;
  #pragma unroll
  for (int qm = 0; qm < 2; ++qm)
    #pragma unroll
    for (int qn = 0; qn < 2; ++qn)
      #pragma unroll
      for (int mf = 0; mf < 4; ++mf)
        #pragma unroll
        for (int nf = 0; nf < 2; ++nf)
          #pragma unroll
          for (int r = 0; r < 4; ++r) {
            const int row = m0 + qm * 128 + wm * 64 + mf * 16 + lrow + r;
            const int col = n0 + qn * 128 + wn * 32 + nf * 16 + lcol;
            C[(size_t)row * N_COL + col] = f2bf_rne(acc[qm][qn][mf][nf][r]);
          }
#undef PHASE
#undef VMC
#undef STG_A
#undef STG_B
}

// ---------------------------------------------------------------------------
// s1q: strip sums of uhat over j (routing iter-1 up to a scale; squash is
// scale-invariant so the 1/16 is dropped).  Block = (b, s): sums 64 j's.
// Restored as a separate kernel — R7 measured: fusing into the gemm epilogue
// costs VGPR/occupancy (72->96, 26->21%) and is a net loss; this kernel runs
// at its ~10 us HBM roofline.
// ---------------------------------------------------------------------------
__global__ __launch_bounds__(256) void s1q(
    const unsigned short* __restrict__ uhat, float* __restrict__ S1q) {
  const int t = threadIdx.x;
  const int b = blockIdx.x >> 3, s = blockIdx.x & 7;
  const unsigned short* up =
      uhat + (size_t)(b * N_IN + s * 64) * N_COL + t * 4;
  float4 a = make_float4(0.f, 0.f, 0.f, 0.f);
  #pragma unroll 8
  for (int j = 0; j < 64; ++j, up += N_COL) {
    const uint2 d = *(const uint2*)up;
    a.x += bf2f(d.x & 0xffffu);
    a.y += __uint_as_float(d.x & 0xffff0000u);
    a.z += bf2f(d.y & 0xffffu);
    a.w += __uint_as_float(d.y & 0xffff0000u);
  }
  *(float4*)&S1q[(size_t)blockIdx.x * 1024 + t * 4] = a;
}

// ---------------------------------------------------------------------------
// Routing iteration: block=(b,jt4).  Phase A (redundant, cheap): sum nstrips
// 1024-float strips of Vin -> s, squash -> v.  Phase B: wave w handles
// jt=jt4*4+w (8 j's); lane l holds uhat[b, i=l>>2, j, k=(l&3)*16..+16];
// b_i dot via quad shuffles; softmax over i (no max-subtract, |b| bounded);
// accumulate c*u; 4-wave LDS reduce -> Pout[blockIdx][i*64+k].
// ---------------------------------------------------------------------------
__global__ __launch_bounds__(256) void route_mid(
    const unsigned short* __restrict__ uhat,
    const float* __restrict__ Vin,
    float* __restrict__ Pout,
    const int nstrips) {
  __shared__ float sq[16 * 68];
  __shared__ float red[4][1024];
  const int t = threadIdx.x;
  const int w = t >> 6, lane = t & 63;
  const int b = blockIdx.x >> 4, jt4 = blockIdx.x & 15;
  const int jt = jt4 * 4 + w;
  const int i_l = lane >> 2, c4 = lane & 3;

  float4 v4 = make_float4(0.f, 0.f, 0.f, 0.f);
  for (int s = 0; s < nstrips; ++s) {
    const float4 ps = *(const float4*)&Vin[((size_t)b * nstrips + s) * 1024 + t * 4];
    v4.x += ps.x; v4.y += ps.y; v4.z += ps.z; v4.w += ps.w;
  }
  float ss = v4.x * v4.x + v4.y * v4.y + v4.z * v4.z + v4.w * v4.w;
  #pragma unroll
  for (int d = 1; d < 16; d <<= 1) ss += __shfl_xor(ss, d);  // 16 lanes = one capsule
  const float inv = 1.f / sqrtf(ss + 1e-7f);
  const int oi = t >> 4, ok = (t & 15) * 4;
  *(float4*)&sq[oi * 68 + ok] =
      make_float4(v4.x * inv, v4.y * inv, v4.z * inv, v4.w * inv);
  __syncthreads();

  float pv[16];
  #pragma unroll
  for (int q = 0; q < 4; q++)
    *(float4*)&pv[q * 4] = *(const float4*)&sq[i_l * 68 + c4 * 16 + q * 4];

  float acc[16];
  #pragma unroll
  for (int q = 0; q < 16; q++) acc[q] = 0.f;

  const unsigned short* ub =
      uhat + (size_t)(b * N_IN + jt * 8) * N_COL + lane * 16;

  for (int jj = 0; jj < 8; ++jj, ub += N_COL) {
    const uint4 d0 = *(const uint4*)ub;
    const uint4 d1 = *(const uint4*)(ub + 8);
    float u[16];
    #define UNP(wd, o) { u[(o)] = bf2f((wd) & 0xffffu); u[(o)+1] = __uint_as_float((wd) & 0xffff0000u); }
    UNP(d0.x, 0) UNP(d0.y, 2) UNP(d0.z, 4) UNP(d0.w, 6)
    UNP(d1.x, 8) UNP(d1.y, 10) UNP(d1.z, 12) UNP(d1.w, 14)
    #undef UNP

    float dot = 0.f;
    #pragma unroll
    for (int q = 0; q < 16; q++) dot = fmaf(pv[q], u[q], dot);
    dot += __shfl_xor(dot, 1);
    dot += __shfl_xor(dot, 2);
    const float e = __expf(dot);
    float s = e;
    #pragma unroll
    for (int d = 4; d < 64; d <<= 1) s += __shfl_xor(s, d);
    const float c = e / s;
    #pragma unroll
    for (int q = 0; q < 16; q++) acc[q] = fmaf(c, u[q], acc[q]);
  }

  #pragma unroll
  for (int q = 0; q < 4; q++)
    *(float4*)&red[w][lane * 16 + q * 4] = make_float4(
        acc[q * 4 + 0], acc[q * 4 + 1], acc[q * 4 + 2], acc[q * 4 + 3]);
  __syncthreads();
  float4 s4 = make_float4(0.f, 0.f, 0.f, 0.f);
  #pragma unroll
  for (int ww = 0; ww < 4; ++ww) {
    const float4 r = *(const float4*)&red[ww][t * 4];
    s4.x += r.x; s4.y += r.y; s4.z += r.z; s4.w += r.w;
  }
  *(float4*)&Pout[(size_t)blockIdx.x * 1024 + t * 4] = s4;
}

// ---------------------------------------------------------------------------
__global__ __launch_bounds__(64) void route_last(
    const float* __restrict__ P, float* __restrict__ dst) {
  const int bi = blockIdx.x;
  const int k = threadIdx.x;
  const int b = bi >> 4, i = bi & 15;
  const float* p = P + (size_t)b * 16 * 1024 + i * 64 + k;
  float s = 0.f;
  #pragma unroll
  for (int tt = 0; tt < 16; ++tt) s += p[(size_t)tt * 1024];
  float ss = s * s;
  #pragma unroll
  for (int d = 1; d < 64; d <<= 1) ss += __shfl_xor(ss, d);
  dst[bi * 64 + k] = s / sqrtf(ss + 1e-7f);
}

// ---------------------------------------------------------------------------
extern "C" void kernel_launch(void* const* d_in, const int* in_sizes, int n_in,
                              void* d_out, int out_size, void* d_ws, size_t ws_size,
                              hipStream_t stream) {
  const float* x = (const float*)d_in[0];   // [64][512][1024] fp32
  const float* W = (const float*)d_in[1];   // [1][1024][1024] fp32
  float* out = (float*)d_out;               // [64][16][64] fp32

  char* ws = (char*)d_ws;
  unsigned short* Wt   = (unsigned short*)ws;                            // 0..2 MB
  unsigned short* uhat = (unsigned short*)(ws + (size_t)(2 << 20));      // 2..66 MB
  unsigned short* xb   = (unsigned short*)(ws + (size_t)66 * (1 << 20)); // 66..130 (dead after gemm)
  float* S1 = (float*)(ws + (size_t)130 * (1 << 20));                    // 130..132 MB
  float* P1 = (float*)(ws + (size_t)66 * (1 << 20));   // reuses dead xb
  float* P2 = (float*)(ws + (size_t)71 * (1 << 20));   // reuses dead xb

  prep<<<16384 + 1024, 256, 0, stream>>>(x, W, xb, Wt);
  gemm_uhat<<<512, 512, 0, stream>>>(xb, Wt, uhat);
  s1q<<<512, 256, 0, stream>>>(uhat, S1);
  route_mid<<<1024, 256, 0, stream>>>(uhat, S1, P1, 8);   // routing iter 2
  route_mid<<<1024, 256, 0, stream>>>(uhat, P1, P2, 16);  // routing iter 3
  route_last<<<1024, 64, 0, stream>>>(P2, out);
}

// Round 3
// 305.935 us; speedup vs baseline: 1.0807x; 1.0223x over previous
//
#include <hip/hip_runtime.h>
#include <stdint.h>

#define NUM_CAP 16
#define DIM_CAP 64
#define BATCH   64
#define N_IN    512
#define D_IN    1024
#define N_COL   1024
#define M_ROWS  (BATCH*N_IN)

typedef __attribute__((ext_vector_type(8))) short short8;
typedef __attribute__((ext_vector_type(4))) float f32x4;

__device__ __forceinline__ float bf2f(unsigned int u) {
  return __uint_as_float(u << 16);
}
__device__ __forceinline__ unsigned short f2bf_rne(float f) {
  unsigned int x = __float_as_uint(f);
  x += 0x7fffu + ((x >> 16) & 1u);
  return (unsigned short)(x >> 16);
}
__device__ __forceinline__ unsigned int pack_rne(unsigned int lo, unsigned int hi) {
  const unsigned int lr = lo + (0x7fffu + ((lo >> 16) & 1u));
  const unsigned int hr = hi + (0x7fffu + ((hi >> 16) & 1u));
  return (lr >> 16) | (hr & 0xffff0000u);
}

// ---------------------------------------------------------------------------
// prep: blocks [0,16384) convert x fp32->bf16 (8 elems/thread, coalesced);
// blocks [16384, 16384+1024) transpose+convert W -> Wt[n][k].
// ---------------------------------------------------------------------------
__global__ __launch_bounds__(256) void prep(
    const float* __restrict__ x, const float* __restrict__ W,
    unsigned short* __restrict__ xb, unsigned short* __restrict__ Wt) {
  const int t = threadIdx.x;
  if (blockIdx.x < 16384) {
    const size_t i = ((size_t)blockIdx.x * 256 + t) * 8;
    const uint4 a = *(const uint4*)(x + i);
    const uint4 b = *(const uint4*)(x + i + 4);
    uint4 p;
    p.x = pack_rne(a.x, a.y); p.y = pack_rne(a.z, a.w);
    p.z = pack_rne(b.x, b.y); p.w = pack_rne(b.z, b.w);
    *(uint4*)(xb + i) = p;
  } else {
    __shared__ float tile[32][33];
    const int bid = blockIdx.x - 16384;       // 0..1023
    const int bx = bid & 31, by = bid >> 5;   // 32x32 tiles
    const int tx = t & 31, ty0 = t >> 5;      // 8 rows per pass
    #pragma unroll
    for (int r = 0; r < 4; r++) {
      const int ty = ty0 + r * 8;
      tile[ty][tx] = W[(size_t)(by * 32 + ty) * N_COL + bx * 32 + tx];
    }
    __syncthreads();
    #pragma unroll
    for (int r = 0; r < 4; r++) {
      const int ty = ty0 + r * 8;
      Wt[(size_t)(bx * 32 + ty) * D_IN + by * 32 + tx] = f2bf_rne(tile[tx][ty]);
    }
  }
}

// ---------------------------------------------------------------------------
// GEMM — 256^2 x BK64 8-phase schedule (T2+T3+T4+T5 port, plain HIP).
// 8 waves as 2(m) x 4(n); wave tile 128x64 from interleaved quadrants:
// wave (wm,wn) at quadrant (qm,qn) computes rows qm*128+wm*64.., cols
// qn*128+wn*32..
//
// R9 (this round): FRAGMENT REGISTER REUSE across quadrant phases.  R8
// measured MfmaUtil 35% (vs template's 62%) with 12 ds_read_b128/phase;
// counting unique frags gives 24/tile but the quadrant loop re-read 48/tile
// (A per qn, B per qm) -> LDS-read pipe was the long pole (~3000 cyc/tile vs
// MFMA ~2480).  Now: quadrant order (0,0)(0,1)(1,1)(1,0); A read at P1/P3;
// B0 kept in dedicated regs P1->P4; B1 read at P2.  24 reads/tile
// (P1:12 P2:4 P3:8 P4:0).  Stage slots, vmcnt counts, region lifetimes
// UNCHANGED from the verified R8 schedule (reuse only shortens LDS-region
// liveness; first-read phases identical, so drain invariants hold).
//
// Stage slots (iter i; u=2i buf0, v=2i+1 buf1):
//   P1: Bh0(v)  P2: Ah1(v)  P3: Ah0(u+2)  P4: Bh1(u+2)
//   P5: Bh0(u+2) P6: Ah1(u+2) P7: Ah0(v+2) P8: Bh1(v+2)
// Waits: end-P2 vmcnt(8), end-P4 vmcnt(6), end-P6 vmcnt(8), end-P8 vmcnt(6);
// last iter: end-P4 vmcnt(2), end-P6 vmcnt(0).
// LDS layout per matrix: [buf][half][kslice 32][128 rows][32 shorts] with the
// verified 4-chunk XOR swizzle (phys chunk = c ^ ((row>>1)&3)); applied on
// the global SOURCE address at stage time (linear LDS dest) and on the
// ds_read address (both-sides involution).  Conflicts measured 0.
// ---------------------------------------------------------------------------
#define LA_OFF(d, h, ks) ((((d)*2 + (h))*2 + (ks)) * 4096)
#define LB_OFF(d, h, ks) (32768 + ((((d)*2 + (h))*2 + (ks)) * 4096))

__global__ __launch_bounds__(512) void gemm_uhat(
    const unsigned short* __restrict__ A,    // [M_ROWS][D_IN] bf16
    const unsigned short* __restrict__ Bt,   // [N_COL][D_IN] bf16
    unsigned short* __restrict__ C) {        // [M_ROWS][N_COL] bf16
  __shared__ __align__(16) unsigned short lds[65536];  // 128 KB: A 0.., B 32768..

  const int t = threadIdx.x;
  const int wave = t >> 6, lane = t & 63;
  const int wm = wave >> 2, wn = wave & 3;

  // XCD map: 512 blocks = 128 mt x 4 nt; xcd owns mt range, nt sweeps fastest
  // so the 4 blocks sharing an A-panel land on the same XCD L2. 512%8==0.
  const int xcd = blockIdx.x & 7, local = blockIdx.x >> 3;
  const int mt = xcd * 16 + (local >> 2), nt = local & 3;
  const int m0 = mt * 256, n0 = nt * 256;

  // staging: thread t covers row srl=t/4 of a 128-row half, 16B chunk t%4,
  // source chunk pre-swizzled so linear LDS dest holds the swizzled layout.
  const int srl = t >> 2;
  const int scz = (t & 3) ^ ((t >> 3) & 3);
  const unsigned short* aBase = A  + (size_t)(m0 + srl) * D_IN + scz * 8;
  const unsigned short* bBase = Bt + (size_t)(n0 + srl) * D_IN + scz * 8;

#define STG_A(kt, h) do { \
    _Pragma("unroll") \
    for (int c_ = 0; c_ < 2; ++c_) \
      __builtin_amdgcn_global_load_lds( \
        (const __attribute__((address_space(1))) void*)(aBase + (size_t)(h)*128*D_IN + (kt)*64 + c_*32), \
        (__attribute__((address_space(3))) void*)(lds + (LA_OFF(((kt)&1), (h), c_)) + t*8), \
        16, 0, 0); \
  } while (0)
#define STG_B(kt, h) do { \
    _Pragma("unroll") \
    for (int c_ = 0; c_ < 2; ++c_) \
      __builtin_amdgcn_global_load_lds( \
        (const __attribute__((address_space(1))) void*)(bBase + (size_t)(h)*128*D_IN + (kt)*64 + c_*32), \
        (__attribute__((address_space(3))) void*)(lds + (LB_OFF(((kt)&1), (h), c_)) + t*8), \
        16, 0, 0); \
  } while (0)

  f32x4 acc[2][2][4][2] = {};  // [qm][qn][mf][nf]

  const int rsel = lane & 15;
  const int koff = ((lane >> 4) ^ ((rsel >> 1) & 3)) * 8;  // swizzled read chunk

  short8 af[4][2], bf0[2][2], bf1[2][2];

#define RD_A(d_, h_) do { \
    _Pragma("unroll") \
    for (int mf = 0; mf < 4; ++mf) \
      _Pragma("unroll") \
      for (int ks = 0; ks < 2; ++ks) \
        af[mf][ks] = *(const short8*)&lds[LA_OFF((d_), (h_), ks) + (wm*64 + mf*16 + rsel)*32 + koff]; \
  } while (0)
#define RD_B(d_, h_, B_) do { \
    _Pragma("unroll") \
    for (int nf = 0; nf < 2; ++nf) \
      _Pragma("unroll") \
      for (int ks = 0; ks < 2; ++ks) \
        B_[nf][ks] = *(const short8*)&lds[LB_OFF((d_), (h_), ks) + (wn*32 + nf*16 + rsel)*32 + koff]; \
  } while (0)

#define PHASE_TAIL(qm_, qn_, B_, WAITS) do { \
    __builtin_amdgcn_s_barrier(); \
    __builtin_amdgcn_s_setprio(1); \
    _Pragma("unroll") \
    for (int ks = 0; ks < 2; ++ks) \
      _Pragma("unroll") \
      for (int mf = 0; mf < 4; ++mf) \
        _Pragma("unroll") \
        for (int nf = 0; nf < 2; ++nf) \
          acc[qm_][qn_][mf][nf] = __builtin_amdgcn_mfma_f32_16x16x32_bf16( \
              af[mf][ks], B_[nf][ks], acc[qm_][qn_][mf][nf], 0, 0, 0); \
    __builtin_amdgcn_s_setprio(0); \
    asm volatile("s_waitcnt lgkmcnt(0)" ::: "memory"); \
    __builtin_amdgcn_sched_barrier(0); \
    WAITS; \
    __builtin_amdgcn_s_barrier(); \
  } while (0)

#define VMC(n) asm volatile("s_waitcnt vmcnt(" #n ")" ::: "memory")

  // prologue: t0 fully + Ah0/Bh1 of t1; drain t0's first 3 halves.
  STG_A(0, 0); STG_B(0, 0); STG_B(0, 1); STG_A(0, 1);
  STG_A(1, 0); STG_B(1, 1);
  VMC(6);
  __builtin_amdgcn_s_barrier();

  for (int i = 0; i < 8; ++i) {
    const int u = 2 * i, v = 2 * i + 1;
    const bool st = (i < 7);
    // ---- tile u (buf0) ----
    RD_A(0, 0); RD_B(0, 0, bf0);
    STG_B(v, 0);
    PHASE_TAIL(0, 0, bf0, {});                                        // P1
    RD_B(0, 1, bf1);
    STG_A(v, 1);
    PHASE_TAIL(0, 1, bf1, { VMC(8); });                               // P2
    RD_A(0, 1);
    if (st) STG_A(u + 2, 0);
    PHASE_TAIL(1, 1, bf1, {});                                        // P3
    if (st) STG_B(u + 2, 1);
    PHASE_TAIL(1, 0, bf0, { if (st) { VMC(6); } else { VMC(2); } });  // P4
    // ---- tile v (buf1) ----
    RD_A(1, 0); RD_B(1, 0, bf0);
    if (st) STG_B(u + 2, 0);
    PHASE_TAIL(0, 0, bf0, {});                                        // P5
    RD_B(1, 1, bf1);
    if (st) STG_A(u + 2, 1);
    PHASE_TAIL(0, 1, bf1, { if (st) { VMC(8); } else { VMC(0); } });  // P6
    RD_A(1, 1);
    if (st) STG_A(v + 2, 0);
    PHASE_TAIL(1, 1, bf1, {});                                        // P7
    if (st) STG_B(v + 2, 1);
    PHASE_TAIL(1, 0, bf0, { VMC(6); });                               // P8
  }

  // C/D layout col=lane&15, row=(lane>>4)*4+reg  [m89-verified]
  const int lrow = (lane >> 4) * 4, lcol = lane & 15;
  #pragma unroll
  for (int qm = 0; qm < 2; ++qm)
    #pragma unroll
    for (int qn = 0; qn < 2; ++qn)
      #pragma unroll
      for (int mf = 0; mf < 4; ++mf)
        #pragma unroll
        for (int nf = 0; nf < 2; ++nf)
          #pragma unroll
          for (int r = 0; r < 4; ++r) {
            const int row = m0 + qm * 128 + wm * 64 + mf * 16 + lrow + r;
            const int col = n0 + qn * 128 + wn * 32 + nf * 16 + lcol;
            C[(size_t)row * N_COL + col] = f2bf_rne(acc[qm][qn][mf][nf][r]);
          }
#undef PHASE_TAIL
#undef RD_A
#undef RD_B
#undef VMC
#undef STG_A
#undef STG_B
}

// ---------------------------------------------------------------------------
// s1q: strip sums of uhat over j (routing iter-1 up to a scale; squash is
// scale-invariant so the 1/16 is dropped).  Block = (b, s): sums 64 j's.
// Kept separate — R7 measured: fusing into the gemm epilogue costs
// VGPR/occupancy (72->96, 26->21%) and is a net loss; this kernel runs at
// its ~10 us HBM roofline.
// ---------------------------------------------------------------------------
__global__ __launch_bounds__(256) void s1q(
    const unsigned short* __restrict__ uhat, float* __restrict__ S1q) {
  const int t = threadIdx.x;
  const int b = blockIdx.x >> 3, s = blockIdx.x & 7;
  const unsigned short* up =
      uhat + (size_t)(b * N_IN + s * 64) * N_COL + t * 4;
  float4 a = make_float4(0.f, 0.f, 0.f, 0.f);
  #pragma unroll 8
  for (int j = 0; j < 64; ++j, up += N_COL) {
    const uint2 d = *(const uint2*)up;
    a.x += bf2f(d.x & 0xffffu);
    a.y += __uint_as_float(d.x & 0xffff0000u);
    a.z += bf2f(d.y & 0xffffu);
    a.w += __uint_as_float(d.y & 0xffff0000u);
  }
  *(float4*)&S1q[(size_t)blockIdx.x * 1024 + t * 4] = a;
}

// ---------------------------------------------------------------------------
// Routing iteration: block=(b,jt4).  Phase A (redundant, cheap): sum nstrips
// 1024-float strips of Vin -> s, squash -> v.  Phase B: wave w handles
// jt=jt4*4+w (8 j's); lane l holds uhat[b, i=l>>2, j, k=(l&3)*16..+16];
// b_i dot via quad shuffles; softmax over i (no max-subtract, |b| bounded);
// accumulate c*u; 4-wave LDS reduce -> Pout[blockIdx][i*64+k].
// ---------------------------------------------------------------------------
__global__ __launch_bounds__(256) void route_mid(
    const unsigned short* __restrict__ uhat,
    const float* __restrict__ Vin,
    float* __restrict__ Pout,
    const int nstrips) {
  __shared__ float sq[16 * 68];
  __shared__ float red[4][1024];
  const int t = threadIdx.x;
  const int w = t >> 6, lane = t & 63;
  const int b = blockIdx.x >> 4, jt4 = blockIdx.x & 15;
  const int jt = jt4 * 4 + w;
  const int i_l = lane >> 2, c4 = lane & 3;

  float4 v4 = make_float4(0.f, 0.f, 0.f, 0.f);
  for (int s = 0; s < nstrips; ++s) {
    const float4 ps = *(const float4*)&Vin[((size_t)b * nstrips + s) * 1024 + t * 4];
    v4.x += ps.x; v4.y += ps.y; v4.z += ps.z; v4.w += ps.w;
  }
  float ss = v4.x * v4.x + v4.y * v4.y + v4.z * v4.z + v4.w * v4.w;
  #pragma unroll
  for (int d = 1; d < 16; d <<= 1) ss += __shfl_xor(ss, d);  // 16 lanes = one capsule
  const float inv = 1.f / sqrtf(ss + 1e-7f);
  const int oi = t >> 4, ok = (t & 15) * 4;
  *(float4*)&sq[oi * 68 + ok] =
      make_float4(v4.x * inv, v4.y * inv, v4.z * inv, v4.w * inv);
  __syncthreads();

  float pv[16];
  #pragma unroll
  for (int q = 0; q < 4; q++)
    *(float4*)&pv[q * 4] = *(const float4*)&sq[i_l * 68 + c4 * 16 + q * 4];

  float acc[16];
  #pragma unroll
  for (int q = 0; q < 16; q++) acc[q] = 0.f;

  const unsigned short* ub =
      uhat + (size_t)(b * N_IN + jt * 8) * N_COL + lane * 16;

  for (int jj = 0; jj < 8; ++jj, ub += N_COL) {
    const uint4 d0 = *(const uint4*)ub;
    const uint4 d1 = *(const uint4*)(ub + 8);
    float u[16];
    #define UNP(wd, o) { u[(o)] = bf2f((wd) & 0xffffu); u[(o)+1] = __uint_as_float((wd) & 0xffff0000u); }
    UNP(d0.x, 0) UNP(d0.y, 2) UNP(d0.z, 4) UNP(d0.w, 6)
    UNP(d1.x, 8) UNP(d1.y, 10) UNP(d1.z, 12) UNP(d1.w, 14)
    #undef UNP

    float dot = 0.f;
    #pragma unroll
    for (int q = 0; q < 16; q++) dot = fmaf(pv[q], u[q], dot);
    dot += __shfl_xor(dot, 1);
    dot += __shfl_xor(dot, 2);
    const float e = __expf(dot);
    float s = e;
    #pragma unroll
    for (int d = 4; d < 64; d <<= 1) s += __shfl_xor(s, d);
    const float c = e / s;
    #pragma unroll
    for (int q = 0; q < 16; q++) acc[q] = fmaf(c, u[q], acc[q]);
  }

  #pragma unroll
  for (int q = 0; q < 4; q++)
    *(float4*)&red[w][lane * 16 + q * 4] = make_float4(
        acc[q * 4 + 0], acc[q * 4 + 1], acc[q * 4 + 2], acc[q * 4 + 3]);
  __syncthreads();
  float4 s4 = make_float4(0.f, 0.f, 0.f, 0.f);
  #pragma unroll
  for (int ww = 0; ww < 4; ++ww) {
    const float4 r = *(const float4*)&red[ww][t * 4];
    s4.x += r.x; s4.y += r.y; s4.z += r.z; s4.w += r.w;
  }
  *(float4*)&Pout[(size_t)blockIdx.x * 1024 + t * 4] = s4;
}

// ---------------------------------------------------------------------------
__global__ __launch_bounds__(64) void route_last(
    const float* __restrict__ P, float* __restrict__ dst) {
  const int bi = blockIdx.x;
  const int k = threadIdx.x;
  const int b = bi >> 4, i = bi & 15;
  const float* p = P + (size_t)b * 16 * 1024 + i * 64 + k;
  float s = 0.f;
  #pragma unroll
  for (int tt = 0; tt < 16; ++tt) s += p[(size_t)tt * 1024];
  float ss = s * s;
  #pragma unroll
  for (int d = 1; d < 64; d <<= 1) ss += __shfl_xor(ss, d);
  dst[bi * 64 + k] = s / sqrtf(ss + 1e-7f);
}

// ---------------------------------------------------------------------------
extern "C" void kernel_launch(void* const* d_in, const int* in_sizes, int n_in,
                              void* d_out, int out_size, void* d_ws, size_t ws_size,
                              hipStream_t stream) {
  const float* x = (const float*)d_in[0];   // [64][512][1024] fp32
  const float* W = (const float*)d_in[1];   // [1][1024][1024] fp32
  float* out = (float*)d_out;               // [64][16][64] fp32

  char* ws = (char*)d_ws;
  unsigned short* Wt   = (unsigned short*)ws;                            // 0..2 MB
  unsigned short* uhat = (unsigned short*)(ws + (size_t)(2 << 20));      // 2..66 MB
  unsigned short* xb   = (unsigned short*)(ws + (size_t)66 * (1 << 20)); // 66..130 (dead after gemm)
  float* S1 = (float*)(ws + (size_t)130 * (1 << 20));                    // 130..132 MB
  float* P1 = (float*)(ws + (size_t)66 * (1 << 20));   // reuses dead xb
  float* P2 = (float*)(ws + (size_t)71 * (1 << 20));   // reuses dead xb

  prep<<<16384 + 1024, 256, 0, stream>>>(x, W, xb, Wt);
  gemm_uhat<<<512, 512, 0, stream>>>(xb, Wt, uhat);
  s1q<<<512, 256, 0, stream>>>(uhat, S1);
  route_mid<<<1024, 256, 0, stream>>>(uhat, S1, P1, 8);   // routing iter 2
  route_mid<<<1024, 256, 0, stream>>>(uhat, P1, P2, 16);  // routing iter 3
  route_last<<<1024, 64, 0, stream>>>(P2, out);
}

// Round 4
// 303.957 us; speedup vs baseline: 1.0878x; 1.0065x over previous
//
#include <hip/hip_runtime.h>
#include <stdint.h>

#define NUM_CAP 16
#define DIM_CAP 64
#define BATCH   64
#define N_IN    512
#define D_IN    1024
#define N_COL   1024
#define M_ROWS  (BATCH*N_IN)

typedef __attribute__((ext_vector_type(8))) short short8;
typedef __attribute__((ext_vector_type(4))) float f32x4;

__device__ __forceinline__ float bf2f(unsigned int u) {
  return __uint_as_float(u << 16);
}
__device__ __forceinline__ unsigned short f2bf_rne(float f) {
  unsigned int x = __float_as_uint(f);
  x += 0x7fffu + ((x >> 16) & 1u);
  return (unsigned short)(x >> 16);
}
__device__ __forceinline__ unsigned int pack_rne(unsigned int lo, unsigned int hi) {
  const unsigned int lr = lo + (0x7fffu + ((lo >> 16) & 1u));
  const unsigned int hr = hi + (0x7fffu + ((hi >> 16) & 1u));
  return (lr >> 16) | (hr & 0xffff0000u);
}

// ---------------------------------------------------------------------------
// prep: blocks [0,16384) convert x fp32->bf16 (8 elems/thread, coalesced);
// blocks [16384, 16384+1024) transpose+convert W -> Wt[n][k].
// ---------------------------------------------------------------------------
__global__ __launch_bounds__(256) void prep(
    const float* __restrict__ x, const float* __restrict__ W,
    unsigned short* __restrict__ xb, unsigned short* __restrict__ Wt) {
  const int t = threadIdx.x;
  if (blockIdx.x < 16384) {
    const size_t i = ((size_t)blockIdx.x * 256 + t) * 8;
    const uint4 a = *(const uint4*)(x + i);
    const uint4 b = *(const uint4*)(x + i + 4);
    uint4 p;
    p.x = pack_rne(a.x, a.y); p.y = pack_rne(a.z, a.w);
    p.z = pack_rne(b.x, b.y); p.w = pack_rne(b.z, b.w);
    *(uint4*)(xb + i) = p;
  } else {
    __shared__ float tile[32][33];
    const int bid = blockIdx.x - 16384;       // 0..1023
    const int bx = bid & 31, by = bid >> 5;   // 32x32 tiles
    const int tx = t & 31, ty0 = t >> 5;      // 8 rows per pass
    #pragma unroll
    for (int r = 0; r < 4; r++) {
      const int ty = ty0 + r * 8;
      tile[ty][tx] = W[(size_t)(by * 32 + ty) * N_COL + bx * 32 + tx];
    }
    __syncthreads();
    #pragma unroll
    for (int r = 0; r < 4; r++) {
      const int ty = ty0 + r * 8;
      Wt[(size_t)(bx * 32 + ty) * D_IN + by * 32 + tx] = f2bf_rne(tile[tx][ty]);
    }
  }
}

// ---------------------------------------------------------------------------
// GEMM — 256^2 x BK64 8-phase schedule (T2+T3+T4+T5 port, plain HIP).
// 8 waves as 2(m) x 4(n); wave tile 128x64 from interleaved quadrants.
//
// R10 (this round): TAIL-SLOT A-FRAGMENT PREFETCH.  R9's per-phase read
// counts {12,4,8,0} put 1150/770 cyc LDS bursts serially in the same
// barrier slot as the 541-cyc MFMA cluster (model: tile = sum of
// (reads*96 + 541) = 4975 cyc — matches measured ~5400).  The staging
// FIFO ledger shows each af-half is drained by EXACTLY one counted wait:
//   P2 vmcnt(8) -> A(u,h1); P4 vmcnt(6) -> A(v,h0);
//   P6 vmcnt(8) -> A(v,h1); P8 vmcnt(6) -> A(u+2,h0).
// So af reads move to the tail slot [vmcnt -> barrier], hidden under the
// HBM drain; body reads drop to {4,4,0,0} (bf0/bf1 only).  Hazards audited:
// every region's last read completes >=1 lgkmcnt(0)+barrier before its
// overwriting stage issues (incl. cross-wave WAR and the loop-boundary P8
// prefetch, fed in the prologue for iter 0; last iter's vmcnt(2)/(0) still
// drain each prefetch's data; P8 prefetch guarded st).  Stage slots and
// wait counts IDENTICAL to the verified R8/R9 schedule.  No new registers
// (af set reused; tail writes follow that phase's af-consuming MFMAs).
//
// Stage slots (iter i; u=2i buf0, v=2i+1 buf1):
//   P1: Bh0(v)  P2: Ah1(v)  P3: Ah0(u+2)  P4: Bh1(u+2)
//   P5: Bh0(u+2) P6: Ah1(u+2) P7: Ah0(v+2) P8: Bh1(v+2)
// Waits: end-P2 vmcnt(8), end-P4 vmcnt(6), end-P6 vmcnt(8), end-P8 vmcnt(6);
// last iter: end-P4 vmcnt(2), end-P6 vmcnt(0).
// LDS layout per matrix: [buf][half][kslice 32][128 rows][32 shorts] with the
// verified 4-chunk XOR swizzle (phys chunk = c ^ ((row>>1)&3)); applied on
// the global SOURCE address at stage time (linear LDS dest) and on the
// ds_read address (both-sides involution).  Conflicts measured 0.
// ---------------------------------------------------------------------------
#define LA_OFF(d, h, ks) ((((d)*2 + (h))*2 + (ks)) * 4096)
#define LB_OFF(d, h, ks) (32768 + ((((d)*2 + (h))*2 + (ks)) * 4096))

__global__ __launch_bounds__(512) void gemm_uhat(
    const unsigned short* __restrict__ A,    // [M_ROWS][D_IN] bf16
    const unsigned short* __restrict__ Bt,   // [N_COL][D_IN] bf16
    unsigned short* __restrict__ C) {        // [M_ROWS][N_COL] bf16
  __shared__ __align__(16) unsigned short lds[65536];  // 128 KB: A 0.., B 32768..

  const int t = threadIdx.x;
  const int wave = t >> 6, lane = t & 63;
  const int wm = wave >> 2, wn = wave & 3;

  // XCD map: 512 blocks = 128 mt x 4 nt; xcd owns mt range, nt sweeps fastest
  // so the 4 blocks sharing an A-panel land on the same XCD L2. 512%8==0.
  const int xcd = blockIdx.x & 7, local = blockIdx.x >> 3;
  const int mt = xcd * 16 + (local >> 2), nt = local & 3;
  const int m0 = mt * 256, n0 = nt * 256;

  // staging: thread t covers row srl=t/4 of a 128-row half, 16B chunk t%4,
  // source chunk pre-swizzled so linear LDS dest holds the swizzled layout.
  const int srl = t >> 2;
  const int scz = (t & 3) ^ ((t >> 3) & 3);
  const unsigned short* aBase = A  + (size_t)(m0 + srl) * D_IN + scz * 8;
  const unsigned short* bBase = Bt + (size_t)(n0 + srl) * D_IN + scz * 8;

#define STG_A(kt, h) do { \
    _Pragma("unroll") \
    for (int c_ = 0; c_ < 2; ++c_) \
      __builtin_amdgcn_global_load_lds( \
        (const __attribute__((address_space(1))) void*)(aBase + (size_t)(h)*128*D_IN + (kt)*64 + c_*32), \
        (__attribute__((address_space(3))) void*)(lds + (LA_OFF(((kt)&1), (h), c_)) + t*8), \
        16, 0, 0); \
  } while (0)
#define STG_B(kt, h) do { \
    _Pragma("unroll") \
    for (int c_ = 0; c_ < 2; ++c_) \
      __builtin_amdgcn_global_load_lds( \
        (const __attribute__((address_space(1))) void*)(bBase + (size_t)(h)*128*D_IN + (kt)*64 + c_*32), \
        (__attribute__((address_space(3))) void*)(lds + (LB_OFF(((kt)&1), (h), c_)) + t*8), \
        16, 0, 0); \
  } while (0)

  f32x4 acc[2][2][4][2] = {};  // [qm][qn][mf][nf]

  const int rsel = lane & 15;
  const int koff = ((lane >> 4) ^ ((rsel >> 1) & 3)) * 8;  // swizzled read chunk

  short8 af[4][2], bf0[2][2], bf1[2][2];

#define RD_A(d_, h_) do { \
    _Pragma("unroll") \
    for (int mf = 0; mf < 4; ++mf) \
      _Pragma("unroll") \
      for (int ks = 0; ks < 2; ++ks) \
        af[mf][ks] = *(const short8*)&lds[LA_OFF((d_), (h_), ks) + (wm*64 + mf*16 + rsel)*32 + koff]; \
  } while (0)
#define RD_B(d_, h_, B_) do { \
    _Pragma("unroll") \
    for (int nf = 0; nf < 2; ++nf) \
      _Pragma("unroll") \
      for (int ks = 0; ks < 2; ++ks) \
        B_[nf][ks] = *(const short8*)&lds[LB_OFF((d_), (h_), ks) + (wn*32 + nf*16 + rsel)*32 + koff]; \
  } while (0)

  // phase core: barrier -> prio MFMA -> lgkmcnt(0) (all this phase's body
  // reads done) -> sched_barrier.  Tail (VMC / af-prefetch / barrier) is
  // written explicitly at each site.
#define MFMA16(qm_, qn_, B_) do { \
    __builtin_amdgcn_s_barrier(); \
    __builtin_amdgcn_s_setprio(1); \
    _Pragma("unroll") \
    for (int ks = 0; ks < 2; ++ks) \
      _Pragma("unroll") \
      for (int mf = 0; mf < 4; ++mf) \
        _Pragma("unroll") \
        for (int nf = 0; nf < 2; ++nf) \
          acc[qm_][qn_][mf][nf] = __builtin_amdgcn_mfma_f32_16x16x32_bf16( \
              af[mf][ks], B_[nf][ks], acc[qm_][qn_][mf][nf], 0, 0, 0); \
    __builtin_amdgcn_s_setprio(0); \
    asm volatile("s_waitcnt lgkmcnt(0)" ::: "memory"); \
    __builtin_amdgcn_sched_barrier(0); \
  } while (0)

#define VMC(n) asm volatile("s_waitcnt vmcnt(" #n ")" ::: "memory")
#define BAR()  __builtin_amdgcn_s_barrier()

  // prologue: t0 fully + Ah0/Bh1 of t1; drain t0's first 3 halves; pre-read
  // af(tile0,h0) for P1 (its data A00 is drained by this vmcnt).
  STG_A(0, 0); STG_B(0, 0); STG_B(0, 1); STG_A(0, 1);
  STG_A(1, 0); STG_B(1, 1);
  VMC(6);
  RD_A(0, 0);
  BAR();

  for (int i = 0; i < 8; ++i) {
    const int u = 2 * i, v = 2 * i + 1;
    const bool st = (i < 7);
    // ---- tile u (buf0) ----
    // P1 q(0,0): af=h0 (prefetched), bf0 body-read
    RD_B(0, 0, bf0);
    STG_B(v, 0);
    MFMA16(0, 0, bf0);
    BAR();
    // P2 q(0,1): bf1 body-read; tail: vmcnt(8) drains A(u,h1) -> prefetch af h1
    RD_B(0, 1, bf1);
    STG_A(v, 1);
    MFMA16(0, 1, bf1);
    VMC(8);
    RD_A(0, 1);
    BAR();
    // P3 q(1,1): no reads
    if (st) STG_A(u + 2, 0);
    MFMA16(1, 1, bf1);
    BAR();
    // P4 q(1,0): tail: vmcnt drains A(v,h0) -> prefetch af h0 of tile v
    if (st) STG_B(u + 2, 1);
    MFMA16(1, 0, bf0);
    if (st) { VMC(6); } else { VMC(2); }
    RD_A(1, 0);
    BAR();
    // ---- tile v (buf1) ----
    // P5 q(0,0)
    RD_B(1, 0, bf0);
    if (st) STG_B(u + 2, 0);
    MFMA16(0, 0, bf0);
    BAR();
    // P6 q(0,1): tail: vmcnt drains A(v,h1) -> prefetch
    RD_B(1, 1, bf1);
    if (st) STG_A(u + 2, 1);
    MFMA16(0, 1, bf1);
    if (st) { VMC(8); } else { VMC(0); }
    RD_A(1, 1);
    BAR();
    // P7 q(1,1): no reads
    if (st) STG_A(v + 2, 0);
    MFMA16(1, 1, bf1);
    BAR();
    // P8 q(1,0): tail: vmcnt(6) drains A(u+2,h0) -> prefetch for next iter P1
    if (st) STG_B(v + 2, 1);
    MFMA16(1, 0, bf0);
    VMC(6);
    if (st) RD_A(0, 0);
    BAR();
  }

  // C/D layout col=lane&15, row=(lane>>4)*4+reg  [m89-verified]
  const int lrow = (lane >> 4) * 4, lcol = lane & 15;
  #pragma unroll
  for (int qm = 0; qm < 2; ++qm)
    #pragma unroll
    for (int qn = 0; qn < 2; ++qn)
      #pragma unroll
      for (int mf = 0; mf < 4; ++mf)
        #pragma unroll
        for (int nf = 0; nf < 2; ++nf)
          #pragma unroll
          for (int r = 0; r < 4; ++r) {
            const int row = m0 + qm * 128 + wm * 64 + mf * 16 + lrow + r;
            const int col = n0 + qn * 128 + wn * 32 + nf * 16 + lcol;
            C[(size_t)row * N_COL + col] = f2bf_rne(acc[qm][qn][mf][nf][r]);
          }
#undef MFMA16
#undef RD_A
#undef RD_B
#undef VMC
#undef BAR
#undef STG_A
#undef STG_B
}

// ---------------------------------------------------------------------------
// s1q: strip sums of uhat over j (routing iter-1 up to a scale; squash is
// scale-invariant so the 1/16 is dropped).  Block = (b, s): sums 64 j's.
// Kept separate — R7 measured: fusing into the gemm epilogue costs
// VGPR/occupancy (72->96, 26->21%) and is a net loss; this kernel runs at
// its ~10 us HBM roofline.
// ---------------------------------------------------------------------------
__global__ __launch_bounds__(256) void s1q(
    const unsigned short* __restrict__ uhat, float* __restrict__ S1q) {
  const int t = threadIdx.x;
  const int b = blockIdx.x >> 3, s = blockIdx.x & 7;
  const unsigned short* up =
      uhat + (size_t)(b * N_IN + s * 64) * N_COL + t * 4;
  float4 a = make_float4(0.f, 0.f, 0.f, 0.f);
  #pragma unroll 8
  for (int j = 0; j < 64; ++j, up += N_COL) {
    const uint2 d = *(const uint2*)up;
    a.x += bf2f(d.x & 0xffffu);
    a.y += __uint_as_float(d.x & 0xffff0000u);
    a.z += bf2f(d.y & 0xffffu);
    a.w += __uint_as_float(d.y & 0xffff0000u);
  }
  *(float4*)&S1q[(size_t)blockIdx.x * 1024 + t * 4] = a;
}

// ---------------------------------------------------------------------------
// Routing iteration: block=(b,jt4).  Phase A (redundant, cheap): sum nstrips
// 1024-float strips of Vin -> s, squash -> v.  Phase B: wave w handles
// jt=jt4*4+w (8 j's); lane l holds uhat[b, i=l>>2, j, k=(l&3)*16..+16];
// b_i dot via quad shuffles; softmax over i (no max-subtract, |b| bounded);
// accumulate c*u; 4-wave LDS reduce -> Pout[blockIdx][i*64+k].
// ---------------------------------------------------------------------------
__global__ __launch_bounds__(256) void route_mid(
    const unsigned short* __restrict__ uhat,
    const float* __restrict__ Vin,
    float* __restrict__ Pout,
    const int nstrips) {
  __shared__ float sq[16 * 68];
  __shared__ float red[4][1024];
  const int t = threadIdx.x;
  const int w = t >> 6, lane = t & 63;
  const int b = blockIdx.x >> 4, jt4 = blockIdx.x & 15;
  const int jt = jt4 * 4 + w;
  const int i_l = lane >> 2, c4 = lane & 3;

  float4 v4 = make_float4(0.f, 0.f, 0.f, 0.f);
  for (int s = 0; s < nstrips; ++s) {
    const float4 ps = *(const float4*)&Vin[((size_t)b * nstrips + s) * 1024 + t * 4];
    v4.x += ps.x; v4.y += ps.y; v4.z += ps.z; v4.w += ps.w;
  }
  float ss = v4.x * v4.x + v4.y * v4.y + v4.z * v4.z + v4.w * v4.w;
  #pragma unroll
  for (int d = 1; d < 16; d <<= 1) ss += __shfl_xor(ss, d);  // 16 lanes = one capsule
  const float inv = 1.f / sqrtf(ss + 1e-7f);
  const int oi = t >> 4, ok = (t & 15) * 4;
  *(float4*)&sq[oi * 68 + ok] =
      make_float4(v4.x * inv, v4.y * inv, v4.z * inv, v4.w * inv);
  __syncthreads();

  float pv[16];
  #pragma unroll
  for (int q = 0; q < 4; q++)
    *(float4*)&pv[q * 4] = *(const float4*)&sq[i_l * 68 + c4 * 16 + q * 4];

  float acc[16];
  #pragma unroll
  for (int q = 0; q < 16; q++) acc[q] = 0.f;

  const unsigned short* ub =
      uhat + (size_t)(b * N_IN + jt * 8) * N_COL + lane * 16;

  for (int jj = 0; jj < 8; ++jj, ub += N_COL) {
    const uint4 d0 = *(const uint4*)ub;
    const uint4 d1 = *(const uint4*)(ub + 8);
    float u[16];
    #define UNP(wd, o) { u[(o)] = bf2f((wd) & 0xffffu); u[(o)+1] = __uint_as_float((wd) & 0xffff0000u); }
    UNP(d0.x, 0) UNP(d0.y, 2) UNP(d0.z, 4) UNP(d0.w, 6)
    UNP(d1.x, 8) UNP(d1.y, 10) UNP(d1.z, 12) UNP(d1.w, 14)
    #undef UNP

    float dot = 0.f;
    #pragma unroll
    for (int q = 0; q < 16; q++) dot = fmaf(pv[q], u[q], dot);
    dot += __shfl_xor(dot, 1);
    dot += __shfl_xor(dot, 2);
    const float e = __expf(dot);
    float s = e;
    #pragma unroll
    for (int d = 4; d < 64; d <<= 1) s += __shfl_xor(s, d);
    const float c = e / s;
    #pragma unroll
    for (int q = 0; q < 16; q++) acc[q] = fmaf(c, u[q], acc[q]);
  }

  #pragma unroll
  for (int q = 0; q < 4; q++)
    *(float4*)&red[w][lane * 16 + q * 4] = make_float4(
        acc[q * 4 + 0], acc[q * 4 + 1], acc[q * 4 + 2], acc[q * 4 + 3]);
  __syncthreads();
  float4 s4 = make_float4(0.f, 0.f, 0.f, 0.f);
  #pragma unroll
  for (int ww = 0; ww < 4; ++ww) {
    const float4 r = *(const float4*)&red[ww][t * 4];
    s4.x += r.x; s4.y += r.y; s4.z += r.z; s4.w += r.w;
  }
  *(float4*)&Pout[(size_t)blockIdx.x * 1024 + t * 4] = s4;
}

// ---------------------------------------------------------------------------
__global__ __launch_bounds__(64) void route_last(
    const float* __restrict__ P, float* __restrict__ dst) {
  const int bi = blockIdx.x;
  const int k = threadIdx.x;
  const int b = bi >> 4, i = bi & 15;
  const float* p = P + (size_t)b * 16 * 1024 + i * 64 + k;
  float s = 0.f;
  #pragma unroll
  for (int tt = 0; tt < 16; ++tt) s += p[(size_t)tt * 1024];
  float ss = s * s;
  #pragma unroll
  for (int d = 1; d < 64; d <<= 1) ss += __shfl_xor(ss, d);
  dst[bi * 64 + k] = s / sqrtf(ss + 1e-7f);
}

// ---------------------------------------------------------------------------
extern "C" void kernel_launch(void* const* d_in, const int* in_sizes, int n_in,
                              void* d_out, int out_size, void* d_ws, size_t ws_size,
                              hipStream_t stream) {
  const float* x = (const float*)d_in[0];   // [64][512][1024] fp32
  const float* W = (const float*)d_in[1];   // [1][1024][1024] fp32
  float* out = (float*)d_out;               // [64][16][64] fp32

  char* ws = (char*)d_ws;
  unsigned short* Wt   = (unsigned short*)ws;                            // 0..2 MB
  unsigned short* uhat = (unsigned short*)(ws + (size_t)(2 << 20));      // 2..66 MB
  unsigned short* xb   = (unsigned short*)(ws + (size_t)66 * (1 << 20)); // 66..130 (dead after gemm)
  float* S1 = (float*)(ws + (size_t)130 * (1 << 20));                    // 130..132 MB
  float* P1 = (float*)(ws + (size_t)66 * (1 << 20));   // reuses dead xb
  float* P2 = (float*)(ws + (size_t)71 * (1 << 20));   // reuses dead xb

  prep<<<16384 + 1024, 256, 0, stream>>>(x, W, xb, Wt);
  gemm_uhat<<<512, 512, 0, stream>>>(xb, Wt, uhat);
  s1q<<<512, 256, 0, stream>>>(uhat, S1);
  route_mid<<<1024, 256, 0, stream>>>(uhat, S1, P1, 8);   // routing iter 2
  route_mid<<<1024, 256, 0, stream>>>(uhat, P1, P2, 16);  // routing iter 3
  route_last<<<1024, 64, 0, stream>>>(P2, out);
}